// Round 2
// baseline (416.465 us; speedup 1.0000x reference)
//
#include <hip/hip_runtime.h>
#include <hip/hip_bf16.h>

#define N_TOK 16384
#define H_DIM 2048
#define NE 8
#define CHUNK 2048
#define IPE 1024
#define F2 2048

typedef __bf16 bf16;
typedef bf16 bf16x8 __attribute__((ext_vector_type(8)));
typedef float f32x4 __attribute__((ext_vector_type(4)));

typedef __attribute__((address_space(1))) void gvoid;
typedef __attribute__((address_space(3))) void svoid;

__device__ __forceinline__ void gload_lds16(const void* g, void* l) {
  __builtin_amdgcn_global_load_lds((gvoid*)g, (svoid*)l, 16, 0, 0);
}

// ---------------------------------------------------------------------------
// Kernel 1: gather rows by sort_idx (int32!) + fp32 -> bf16 convert
// ---------------------------------------------------------------------------
__global__ __launch_bounds__(256) void k_gather(
    const float* __restrict__ x, const int* __restrict__ sidx,
    bf16* __restrict__ xs) {
  int row = blockIdx.x;
  int src = sidx[row];
  const float4* ip = (const float4*)(x + (size_t)src * H_DIM);
  int t = threadIdx.x;
  float4 f0 = ip[t * 2], f1 = ip[t * 2 + 1];
  bf16x8 v;
  v[0] = (bf16)f0.x; v[1] = (bf16)f0.y; v[2] = (bf16)f0.z; v[3] = (bf16)f0.w;
  v[4] = (bf16)f1.x; v[5] = (bf16)f1.y; v[6] = (bf16)f1.z; v[7] = (bf16)f1.w;
  *(bf16x8*)(xs + (size_t)row * H_DIM + t * 8) = v;
}

// ---------------------------------------------------------------------------
// Kernel 2: gate_up [E][H][2I] fp32 -> w1t [E][F'][H] bf16 with 16-col
// gate/up interleave: f' group g (16 cols): g even -> gate (g/2)*16+w,
// g odd -> up 1024+(g/2)*16+w.
// ---------------------------------------------------------------------------
__global__ __launch_bounds__(256) void k_tr_w1(const float* __restrict__ in,
                                               bf16* __restrict__ out) {
  int e = blockIdx.z;
  int fB = blockIdx.x;  // out f' block (64 wide): gate [fB*32,+32), up [1024+fB*32,+32)
  int hB = blockIdx.y;  // h block (64 wide)
  __shared__ bf16 lds[64][68];
  int tx = threadIdx.x & 63;
  int ty = threadIdx.x >> 6;
  const float* ip = in + ((size_t)e * H_DIM + hB * 64) * F2;
  int scol = (tx < 32) ? (fB * 32 + tx) : (1024 + fB * 32 + (tx - 32));
#pragma unroll
  for (int p = 0; p < 16; ++p) {
    int hl = p * 4 + ty;
    lds[hl][tx] = (bf16)ip[(size_t)hl * F2 + scol];
  }
  __syncthreads();
  bf16* op = out + ((size_t)e * F2 + fB * 64) * H_DIM + hB * 64;
#pragma unroll
  for (int p = 0; p < 16; ++p) {
    int fl = p * 4 + ty;
    int g = fl >> 4, w = fl & 15;
    int lcol = ((g >> 1) << 4) + w + ((g & 1) << 5);
    op[(size_t)fl * H_DIM + tx] = lds[tx][lcol];
  }
}

// ---------------------------------------------------------------------------
// Kernel 3: down [E][I][H] fp32 -> w2t [E][H][I] bf16 (plain transpose)
// ---------------------------------------------------------------------------
__global__ __launch_bounds__(256) void k_tr_w2(const float* __restrict__ in,
                                               bf16* __restrict__ out) {
  int e = blockIdx.z;
  int hB = blockIdx.x;  // 2048/64 = 32
  int iB = blockIdx.y;  // 1024/64 = 16
  __shared__ bf16 lds[64][68];
  int tx = threadIdx.x & 63;
  int ty = threadIdx.x >> 6;
  const float* ip = in + (size_t)e * IPE * H_DIM + (size_t)iB * 64 * H_DIM + hB * 64;
#pragma unroll
  for (int p = 0; p < 16; ++p) {
    int il = p * 4 + ty;
    lds[il][tx] = (bf16)ip[(size_t)il * H_DIM + tx];
  }
  __syncthreads();
  bf16* op = out + (size_t)e * H_DIM * IPE + (size_t)hB * 64 * IPE + iB * 64;
#pragma unroll
  for (int p = 0; p < 16; ++p) {
    int hl = p * 4 + ty;
    op[(size_t)hl * IPE + tx] = lds[tx][hl];
  }
}

// ---------------------------------------------------------------------------
// GEMM1: sorted_x [E*2048][2048] x w1t [E][2048][2048] -> act [E*2048][1024]
// 128x128 tile, BK=32, 4 waves, dbuf global_load_lds, fused SiLU epilogue.
// ---------------------------------------------------------------------------
#define BK 32

__global__ __launch_bounds__(256) void k_gemm1(
    const bf16* __restrict__ X, const bf16* __restrict__ W,
    bf16* __restrict__ act) {
  const int e = blockIdx.z, bm = blockIdx.y, bn = blockIdx.x;
  const int tid = threadIdx.x;
  const int lane = tid & 63, wv = tid >> 6;
  const int wm = wv >> 1, wn = wv & 1;
  __shared__ __align__(16) bf16 As[2][128 * BK];
  __shared__ __align__(16) bf16 Bs[2][128 * BK];
  const char* Ab = (const char*)(X + ((size_t)e * CHUNK + bm * 128) * H_DIM);
  const char* Bb = (const char*)(W + ((size_t)e * F2 + bn * 128) * H_DIM);

  f32x4 acc[4][4] = {};

  auto stage = [&](int buf, int k0) {
#pragma unroll
    for (int r = 0; r < 2; ++r) {
      int o = r * 4096 + wv * 1024 + lane * 16;  // byte offset in 8KB tile
      int row = o >> 6, colb = o & 63;           // 64B per tile row
      gload_lds16(Ab + (size_t)row * (H_DIM * 2) + k0 * 2 + colb,
                  (char*)&As[buf][0] + (r * 4096 + wv * 1024));
      gload_lds16(Bb + (size_t)row * (H_DIM * 2) + k0 * 2 + colb,
                  (char*)&Bs[buf][0] + (r * 4096 + wv * 1024));
    }
  };

  stage(0, 0);
  __syncthreads();
  int cur = 0;
  const int NT = H_DIM / BK;  // 64
  for (int kt = 0; kt < NT; ++kt) {
    if (kt + 1 < NT) stage(cur ^ 1, (kt + 1) * BK);
    bf16x8 af[4], bfr[4];
#pragma unroll
    for (int m = 0; m < 4; ++m)
      af[m] = *(const bf16x8*)&As[cur][(wm * 64 + m * 16 + (lane & 15)) * BK + (lane >> 4) * 8];
#pragma unroll
    for (int n = 0; n < 4; ++n)
      bfr[n] = *(const bf16x8*)&Bs[cur][(wn * 64 + n * 16 + (lane & 15)) * BK + (lane >> 4) * 8];
#pragma unroll
    for (int m = 0; m < 4; ++m)
#pragma unroll
      for (int n = 0; n < 4; ++n)
        acc[m][n] = __builtin_amdgcn_mfma_f32_16x16x32_bf16(af[m], bfr[n], acc[m][n], 0, 0, 0);
    __syncthreads();
    cur ^= 1;
  }

  // epilogue: fragment pairs (2p, 2p+1) = (gate, up), same lane mapping.
  bf16* actp = act + ((size_t)e * CHUNK + bm * 128) * IPE;
  int rbase = wm * 64 + (lane >> 4) * 4;
  int cbase = bn * 64 + wn * 32 + (lane & 15);
#pragma unroll
  for (int m = 0; m < 4; ++m) {
#pragma unroll
    for (int p = 0; p < 2; ++p) {
      f32x4 g = acc[m][2 * p], u = acc[m][2 * p + 1];
#pragma unroll
      for (int r = 0; r < 4; ++r) {
        float gv = g[r];
        float a = gv / (1.f + __expf(-gv)) * u[r];
        actp[(size_t)(rbase + m * 16 + r) * IPE + cbase + p * 16] = (bf16)a;
      }
    }
  }
}

// ---------------------------------------------------------------------------
// GEMM2: act [E*2048][1024] x w2t [E][2048][1024] -> scatter fp32 out rows
// ---------------------------------------------------------------------------
__global__ __launch_bounds__(256) void k_gemm2(
    const bf16* __restrict__ A, const bf16* __restrict__ W,
    const int* __restrict__ sidx, float* __restrict__ out) {
  const int e = blockIdx.z, bm = blockIdx.y, bn = blockIdx.x;
  const int tid = threadIdx.x;
  const int lane = tid & 63, wv = tid >> 6;
  const int wm = wv >> 1, wn = wv & 1;
  __shared__ __align__(16) bf16 As[2][128 * BK];
  __shared__ __align__(16) bf16 Bs[2][128 * BK];
  const char* Ab = (const char*)(A + ((size_t)e * CHUNK + bm * 128) * IPE);
  const char* Bb = (const char*)(W + ((size_t)e * H_DIM + bn * 128) * IPE);

  f32x4 acc[4][4] = {};

  auto stage = [&](int buf, int k0) {
#pragma unroll
    for (int r = 0; r < 2; ++r) {
      int o = r * 4096 + wv * 1024 + lane * 16;
      int row = o >> 6, colb = o & 63;
      gload_lds16(Ab + (size_t)row * (IPE * 2) + k0 * 2 + colb,
                  (char*)&As[buf][0] + (r * 4096 + wv * 1024));
      gload_lds16(Bb + (size_t)row * (IPE * 2) + k0 * 2 + colb,
                  (char*)&Bs[buf][0] + (r * 4096 + wv * 1024));
    }
  };

  stage(0, 0);
  __syncthreads();
  int cur = 0;
  const int NT = IPE / BK;  // 32
  for (int kt = 0; kt < NT; ++kt) {
    if (kt + 1 < NT) stage(cur ^ 1, (kt + 1) * BK);
    bf16x8 af[4], bfr[4];
#pragma unroll
    for (int m = 0; m < 4; ++m)
      af[m] = *(const bf16x8*)&As[cur][(wm * 64 + m * 16 + (lane & 15)) * BK + (lane >> 4) * 8];
#pragma unroll
    for (int n = 0; n < 4; ++n)
      bfr[n] = *(const bf16x8*)&Bs[cur][(wn * 64 + n * 16 + (lane & 15)) * BK + (lane >> 4) * 8];
#pragma unroll
    for (int m = 0; m < 4; ++m)
#pragma unroll
      for (int n = 0; n < 4; ++n)
        acc[m][n] = __builtin_amdgcn_mfma_f32_16x16x32_bf16(af[m], bfr[n], acc[m][n], 0, 0, 0);
    __syncthreads();
    cur ^= 1;
  }

  int rbase = bm * 128 + wm * 64 + (lane >> 4) * 4;
  int cbase = bn * 128 + wn * 64 + (lane & 15);
#pragma unroll
  for (int m = 0; m < 4; ++m) {
#pragma unroll
    for (int r = 0; r < 4; ++r) {
      int dst = sidx[(size_t)e * CHUNK + rbase + m * 16 + r];
      float* op = out + (size_t)dst * H_DIM + cbase;
#pragma unroll
      for (int n = 0; n < 4; ++n) op[n * 16] = acc[m][n][r];
    }
  }
}

// ---------------------------------------------------------------------------
extern "C" void kernel_launch(void* const* d_in, const int* in_sizes, int n_in,
                              void* d_out, int out_size, void* d_ws, size_t ws_size,
                              hipStream_t stream) {
  const float* hidden = (const float*)d_in[0];
  const int* sidx = (const int*)d_in[1];
  const float* w1 = (const float*)d_in[2];
  const float* w2 = (const float*)d_in[3];
  float* out = (float*)d_out;

  // Workspace layout (peak 160 MiB):
  //   [0,   64M)  xs   (gathered bf16 x)      -- live until k_gemm1 done
  //   [0,   32M)  w2t  (bf16 down^T)          -- written AFTER k_gemm1 (aliases xs)
  //   [64, 128M)  w1t  (bf16 gate_up^T interleaved)
  //   [128,160M)  act  (bf16 silu(gate)*up)
  char* ws = (char*)d_ws;
  bf16* xs  = (bf16*)(ws);
  bf16* w1t = (bf16*)(ws + (size_t)67108864);
  bf16* act = (bf16*)(ws + (size_t)134217728);
  bf16* w2t = (bf16*)(ws);

  k_gather<<<dim3(N_TOK), 256, 0, stream>>>(hidden, sidx, xs);
  k_tr_w1<<<dim3(32, 32, NE), 256, 0, stream>>>(w1, w1t);
  k_gemm1<<<dim3(16, 16, NE), 256, 0, stream>>>(xs, w1t, act);
  k_tr_w2<<<dim3(32, 16, NE), 256, 0, stream>>>(w2, w2t);
  k_gemm2<<<dim3(16, 16, NE), 256, 0, stream>>>(act, w2t, sidx, out);
}

// Round 3
// 305.853 us; speedup vs baseline: 1.3617x; 1.3617x over previous
//
#include <hip/hip_runtime.h>
#include <hip/hip_bf16.h>

#define N_TOK 16384
#define H_DIM 2048
#define NE 8
#define CHUNK 2048
#define IPE 1024
#define F2 2048

typedef __bf16 bf16;
typedef bf16 bf16x8 __attribute__((ext_vector_type(8)));
typedef float f32x4 __attribute__((ext_vector_type(4)));

typedef __attribute__((address_space(1))) void gvoid;
typedef __attribute__((address_space(3))) void svoid;

__device__ __forceinline__ void gload_lds16(const void* g, void* l) {
  __builtin_amdgcn_global_load_lds((gvoid*)g, (svoid*)l, 16, 0, 0);
}
__device__ __forceinline__ f32x4 MF(bf16x8 a, bf16x8 b, f32x4 c) {
  return __builtin_amdgcn_mfma_f32_16x16x32_bf16(a, b, c, 0, 0, 0);
}

#define BAR() __builtin_amdgcn_s_barrier()
#define LGKM0() asm volatile("s_waitcnt lgkmcnt(0)" ::: "memory")
#define LGKM8() asm volatile("s_waitcnt lgkmcnt(8)" ::: "memory")
#define VM6() asm volatile("s_waitcnt vmcnt(6)" ::: "memory")
#define VM0() asm volatile("s_waitcnt vmcnt(0)" ::: "memory")
#define PRIO(x) __builtin_amdgcn_s_setprio(x)

// ---------------------------------------------------------------------------
// prep kernels (unchanged, passing)
// ---------------------------------------------------------------------------
__global__ __launch_bounds__(256) void k_gather(
    const float* __restrict__ x, const int* __restrict__ sidx,
    bf16* __restrict__ xs) {
  int row = blockIdx.x;
  int src = sidx[row];
  const float4* ip = (const float4*)(x + (size_t)src * H_DIM);
  int t = threadIdx.x;
  float4 f0 = ip[t * 2], f1 = ip[t * 2 + 1];
  bf16x8 v;
  v[0] = (bf16)f0.x; v[1] = (bf16)f0.y; v[2] = (bf16)f0.z; v[3] = (bf16)f0.w;
  v[4] = (bf16)f1.x; v[5] = (bf16)f1.y; v[6] = (bf16)f1.z; v[7] = (bf16)f1.w;
  *(bf16x8*)(xs + (size_t)row * H_DIM + t * 8) = v;
}

__global__ __launch_bounds__(256) void k_tr_w1(const float* __restrict__ in,
                                               bf16* __restrict__ out) {
  int e = blockIdx.z;
  int fB = blockIdx.x;
  int hB = blockIdx.y;
  __shared__ bf16 lds[64][68];
  int tx = threadIdx.x & 63;
  int ty = threadIdx.x >> 6;
  const float* ip = in + ((size_t)e * H_DIM + hB * 64) * F2;
  int scol = (tx < 32) ? (fB * 32 + tx) : (1024 + fB * 32 + (tx - 32));
#pragma unroll
  for (int p = 0; p < 16; ++p) {
    int hl = p * 4 + ty;
    lds[hl][tx] = (bf16)ip[(size_t)hl * F2 + scol];
  }
  __syncthreads();
  bf16* op = out + ((size_t)e * F2 + fB * 64) * H_DIM + hB * 64;
#pragma unroll
  for (int p = 0; p < 16; ++p) {
    int fl = p * 4 + ty;
    int g = fl >> 4, w = fl & 15;
    int lcol = ((g >> 1) << 4) + w + ((g & 1) << 5);
    op[(size_t)fl * H_DIM + tx] = lds[tx][lcol];
  }
}

__global__ __launch_bounds__(256) void k_tr_w2(const float* __restrict__ in,
                                               bf16* __restrict__ out) {
  int e = blockIdx.z;
  int hB = blockIdx.x;
  int iB = blockIdx.y;
  __shared__ bf16 lds[64][68];
  int tx = threadIdx.x & 63;
  int ty = threadIdx.x >> 6;
  const float* ip = in + (size_t)e * IPE * H_DIM + (size_t)iB * 64 * H_DIM + hB * 64;
#pragma unroll
  for (int p = 0; p < 16; ++p) {
    int il = p * 4 + ty;
    lds[il][tx] = (bf16)ip[(size_t)il * H_DIM + tx];
  }
  __syncthreads();
  bf16* op = out + (size_t)e * H_DIM * IPE + (size_t)hB * 64 * IPE + iB * 64;
#pragma unroll
  for (int p = 0; p < 16; ++p) {
    int hl = p * 4 + ty;
    op[(size_t)hl * IPE + tx] = lds[tx][hl];
  }
}

// ---------------------------------------------------------------------------
// 256x256x64 8-phase grouped GEMM (T2 swizzle + T3/T4 counted vmcnt + T5).
// A [E*2048][KDIM] bf16, B [E*2048][KDIM] bf16 (row = output col).
// SILU: fused silu(gate)*up epilogue -> act bf16 [E*CHUNK][IPE]
// else: scatter fp32 rows via sidx -> fout [N_TOK][H_DIM]
//
// LDS map (128 KiB): buf*65536 + mat*32768 + half*16384; half = 128 rows x
// 64 cols bf16 = 16 KiB, row stride 128 B. Swizzle: byte ^= ((row&7)<<4),
// applied inverse on the global source (LDS dest linear) + on ds_read.
//
// Half-tile ledger (stage order B0,B1,A0,A1; 2 loads each; 1 half/phase):
//   entering tile t: t fully landed, t+1{B0,B1,A0} issued.
//   P0 stages t+1.A1 (nxt buf), P1 t+2.B0, P2 t+2.B1, P3 t+2.A0 (cur buf,
//   regions fully consumed: all B reads issued in P0, all A reads by P2).
//   vmcnt(6) at P3 = exactly t+2's 3 half-tiles in flight.
// ---------------------------------------------------------------------------
template <int KDIM, bool SILU>
__global__ __launch_bounds__(512) void k_gemm8(
    const bf16* __restrict__ Aptr, const bf16* __restrict__ Bptr,
    const int* __restrict__ sidx, bf16* __restrict__ act,
    float* __restrict__ fout) {
  extern __shared__ char smem[];
  const int tid = threadIdx.x, lane = tid & 63, wv = tid >> 6;
  const int wm = wv >> 2, wn = wv & 3;
  constexpr int NT = KDIM / 64;

  // XCD-aware swizzle (gridDim.x = 512, %8 == 0 -> bijective)
  int swzwg = (blockIdx.x & 7) * (gridDim.x >> 3) + (blockIdx.x >> 3);
  const int e = swzwg >> 6, bm = (swzwg >> 3) & 7, bn = swzwg & 7;

  const char* Ab = (const char*)(Aptr + ((size_t)e * CHUNK + bm * 256) * KDIM);
  const char* Bb = (const char*)(Bptr + ((size_t)e * 2048 + bn * 256) * KDIM);

  // staging source coords: LDS linear L -> global tile-linear swz(L)
  const int L0 = wv * 1024 + lane * 16;
  const int lin0 = L0 ^ (((L0 >> 7) & 7) << 4);
  const int srow0 = lin0 >> 7, scolb = lin0 & 127;

  // fragment-read constants
  const int rA = lane & 15;
  const int swzr = (rA & 7) << 4;
  const int cb = (lane >> 4) * 16;

  f32x4 acc[8][4] = {};

  auto stage = [&](int buf, int mat, int half, int kt) {
    const char* gb = (mat == 0) ? Ab : Bb;
    char* ld = smem + buf * 65536 + mat * 32768 + half * 16384 + wv * 1024;
    size_t rb = (size_t)(half * 128 + srow0) * (KDIM * 2) + (size_t)kt * 128 + scolb;
    gload_lds16(gb + rb, ld);
    gload_lds16(gb + rb + (size_t)64 * (KDIM * 2), ld + 8192);
  };
  auto ldA = [&](int buf, int mi, int ks) {
    int lin = ((mi * 16 + rA) << 7) + ks * 64 + cb;
    return *(const bf16x8*)(smem + buf * 65536 + wm * 16384 + (lin ^ swzr));
  };
  auto ldB = [&](int buf, int ni, int ks) {
    int lin = (((wn & 1) * 64 + ni * 16 + rA) << 7) + ks * 64 + cb;
    return *(const bf16x8*)(smem + buf * 65536 + 32768 + (wn >> 1) * 16384 + (lin ^ swzr));
  };

  // prologue: tile0 {B0,B1,A0,A1}, tile1 {B0,B1,A0}; wait tile0 landed.
  stage(0, 1, 0, 0); stage(0, 1, 1, 0); stage(0, 0, 0, 0); stage(0, 0, 1, 0);
  stage(1, 1, 0, 1); stage(1, 1, 1, 1); stage(1, 0, 0, 1);
  VM6();
  BAR();

  for (int t = 0; t < NT; ++t) {
    const int cur = t & 1, nxt = cur ^ 1;
    bf16x8 b0[4], b1[4], a0[4], a1[4], a2[4];
    // ---- P0: reads B(all,ks0/1) + A(mi0-3,ks0); stage t+1.A1 ----
#pragma unroll
    for (int ni = 0; ni < 4; ++ni) { b0[ni] = ldB(cur, ni, 0); b1[ni] = ldB(cur, ni, 1); }
#pragma unroll
    for (int mi = 0; mi < 4; ++mi) a0[mi] = ldA(cur, mi, 0);
    if (t + 1 < NT) stage(nxt, 0, 1, t + 1);
    LGKM8();
    BAR();
    LGKM0();
    PRIO(1);
#pragma unroll
    for (int mi = 0; mi < 4; ++mi)
#pragma unroll
      for (int ni = 0; ni < 4; ++ni) acc[mi][ni] = MF(a0[mi], b0[ni], acc[mi][ni]);
    PRIO(0);
    BAR();
    // ---- P1: reads A(mi0-3,ks1) + A(mi4-7,ks0); stage t+2.B0 ----
#pragma unroll
    for (int mi = 0; mi < 4; ++mi) a1[mi] = ldA(cur, mi, 1);
#pragma unroll
    for (int mi = 0; mi < 4; ++mi) a2[mi] = ldA(cur, 4 + mi, 0);
    if (t + 2 < NT) stage(cur, 1, 0, t + 2);
    BAR();
    LGKM0();
    PRIO(1);
#pragma unroll
    for (int mi = 0; mi < 4; ++mi)
#pragma unroll
      for (int ni = 0; ni < 4; ++ni) acc[mi][ni] = MF(a1[mi], b1[ni], acc[mi][ni]);
    PRIO(0);
    BAR();
    // ---- P2: reads A(mi4-7,ks1); stage t+2.B1 ----
#pragma unroll
    for (int mi = 0; mi < 4; ++mi) a0[mi] = ldA(cur, 4 + mi, 1);
    if (t + 2 < NT) stage(cur, 1, 1, t + 2);
    BAR();
    LGKM0();
    PRIO(1);
#pragma unroll
    for (int mi = 0; mi < 4; ++mi)
#pragma unroll
      for (int ni = 0; ni < 4; ++ni) acc[4 + mi][ni] = MF(a2[mi], b0[ni], acc[4 + mi][ni]);
    PRIO(0);
    BAR();
    // ---- P3: stage t+2.A0; counted vmcnt; last quadrant ----
    if (t + 2 < NT) {
      stage(cur, 0, 0, t + 2);
      VM6();
    } else if (t + 1 < NT) {
      VM0();
    }
    BAR();
    PRIO(1);
#pragma unroll
    for (int mi = 0; mi < 4; ++mi)
#pragma unroll
      for (int ni = 0; ni < 4; ++ni) acc[4 + mi][ni] = MF(a0[mi], b1[ni], acc[4 + mi][ni]);
    PRIO(0);
    BAR();
  }

  if constexpr (SILU) {
    // fragment pairs (2p, 2p+1) = (gate, up); act col = bn*128+wn*32+(ni>>1)*16
    bf16* actp = act + ((size_t)e * CHUNK + bm * 256 + wm * 128) * IPE;
    const int r0 = (lane >> 4) * 4;
    const int c0 = bn * 128 + wn * 32 + (lane & 15);
#pragma unroll
    for (int mi = 0; mi < 8; ++mi)
#pragma unroll
      for (int p = 0; p < 2; ++p) {
        f32x4 g = acc[mi][2 * p], u = acc[mi][2 * p + 1];
#pragma unroll
        for (int r = 0; r < 4; ++r) {
          float gv = g[r];
          float a = gv / (1.f + __expf(-gv)) * u[r];
          actp[(size_t)(mi * 16 + r0 + r) * IPE + c0 + p * 16] = (bf16)a;
        }
      }
  } else {
    const int* sp = sidx + e * CHUNK + bm * 256 + wm * 128;
    const int r0 = (lane >> 4) * 4;
    const int c0 = bn * 256 + wn * 64 + (lane & 15);
#pragma unroll
    for (int mi = 0; mi < 8; ++mi)
#pragma unroll
      for (int r = 0; r < 4; ++r) {
        int dst = sp[mi * 16 + r0 + r];
        float* op = fout + (size_t)dst * H_DIM + c0;
#pragma unroll
        for (int ni = 0; ni < 4; ++ni) op[ni * 16] = acc[mi][ni][r];
      }
  }
}

// ---------------------------------------------------------------------------
extern "C" void kernel_launch(void* const* d_in, const int* in_sizes, int n_in,
                              void* d_out, int out_size, void* d_ws, size_t ws_size,
                              hipStream_t stream) {
  const float* hidden = (const float*)d_in[0];
  const int* sidx = (const int*)d_in[1];
  const float* w1 = (const float*)d_in[2];
  const float* w2 = (const float*)d_in[3];
  float* out = (float*)d_out;

  // Workspace (peak 160 MiB):
  //   [0,   64M)  xs  -- live until gemm1 done; w2t aliases it afterwards
  //   [64, 128M)  w1t
  //   [128,160M)  act
  char* ws = (char*)d_ws;
  bf16* xs  = (bf16*)(ws);
  bf16* w1t = (bf16*)(ws + (size_t)67108864);
  bf16* act = (bf16*)(ws + (size_t)134217728);
  bf16* w2t = (bf16*)(ws);

  hipFuncSetAttribute((const void*)k_gemm8<H_DIM, true>,
                      hipFuncAttributeMaxDynamicSharedMemorySize, 131072);
  hipFuncSetAttribute((const void*)k_gemm8<IPE, false>,
                      hipFuncAttributeMaxDynamicSharedMemorySize, 131072);

  k_gather<<<dim3(N_TOK), 256, 0, stream>>>(hidden, sidx, xs);
  k_tr_w1<<<dim3(32, 32, NE), 256, 0, stream>>>(w1, w1t);
  k_gemm8<H_DIM, true><<<dim3(512), 512, 131072, stream>>>(xs, w1t, nullptr, act, nullptr);
  k_tr_w2<<<dim3(32, 16, NE), 256, 0, stream>>>(w2, w2t);
  k_gemm8<IPE, false><<<dim3(512), 512, 131072, stream>>>(act, w2t, sidx, nullptr, out);
}